// Round 1
// baseline (223.590 us; speedup 1.0000x reference)
//
#include <hip/hip_runtime.h>
#include <math.h>

#define EPSV 1e-8f

constexpr int D  = 1024;
constexpr int E  = 64;
constexpr int TB = 32;    // tokens per block
constexpr int TW = 8;     // tokens per wave
constexpr int DC = 128;   // d-chunk
constexpr int PAD = 132;  // padded LDS row stride in floats (16B-aligned, bank-spread)

// ---------- expert inverse norms ----------
__global__ __launch_bounds__(256) void expert_norm_kernel(const float* __restrict__ expw,
                                                          float* __restrict__ einv) {
  const int b = blockIdx.x;
  const int tid = threadIdx.x;
  const float4 v = *reinterpret_cast<const float4*>(expw + (size_t)b * D + tid * 4);
  float ss = v.x * v.x + v.y * v.y + v.z * v.z + v.w * v.w;
#pragma unroll
  for (int m = 32; m >= 1; m >>= 1) ss += __shfl_xor(ss, m);
  __shared__ float red[4];
  if ((tid & 63) == 0) red[tid >> 6] = ss;
  __syncthreads();
  if (tid == 0) {
    float t = (red[0] + red[1]) + (red[2] + red[3]);
    einv[b] = 1.0f / (sqrtf(t) + EPSV);
  }
}

// ---------- main gating kernel ----------
__global__ __launch_bounds__(256) void gate_kernel(const float* __restrict__ tok,
                                                   const float* __restrict__ expw,
                                                   const float* __restrict__ cache,
                                                   const float* __restrict__ einv_g,
                                                   float* __restrict__ out_idx,
                                                   float* __restrict__ out_w) {
  __shared__ float s_tok[TB][PAD];
  __shared__ float s_exp[E][PAD];
  __shared__ float s_sq[TB][8];
  __shared__ float s_tinv[TB];

  const int tid = threadIdx.x;
  const int lane = tid & 63;
  const int wid = tid >> 6;
  const int bt = blockIdx.x * TB;

  const float einv = einv_g[lane];         // lane == expert id
  const float bonus = 0.1f * cache[lane];

  float acc[TW][4];
#pragma unroll
  for (int t = 0; t < TW; ++t)
#pragma unroll
    for (int j = 0; j < 4; ++j) acc[t][j] = 0.f;

  float sq = 0.f;
  const int tr = tid >> 3, tp = tid & 7;  // token staging: 8 threads/row, 16 floats each
  const int er = tid >> 2, ep = tid & 3;  // expert staging: 4 threads/row, 32 floats each

#pragma unroll 1
  for (int c = 0; c < D / DC; ++c) {
    const int d0 = c * DC;
    {  // stage tokens + accumulate this thread's sumsq share
      const float4* g = reinterpret_cast<const float4*>(tok + (size_t)(bt + tr) * D + d0 + tp * 16);
      float4 a0 = g[0], a1 = g[1], a2 = g[2], a3 = g[3];
      float4* s = reinterpret_cast<float4*>(&s_tok[tr][tp * 16]);
      s[0] = a0; s[1] = a1; s[2] = a2; s[3] = a3;
      sq += a0.x * a0.x + a0.y * a0.y + a0.z * a0.z + a0.w * a0.w;
      sq += a1.x * a1.x + a1.y * a1.y + a1.z * a1.z + a1.w * a1.w;
      sq += a2.x * a2.x + a2.y * a2.y + a2.z * a2.z + a2.w * a2.w;
      sq += a3.x * a3.x + a3.y * a3.y + a3.z * a3.z + a3.w * a3.w;
    }
    {  // stage experts
      const float4* g = reinterpret_cast<const float4*>(expw + (size_t)er * D + d0 + ep * 32);
      float4* s = reinterpret_cast<float4*>(&s_exp[er][ep * 32]);
#pragma unroll
      for (int i = 0; i < 8; ++i) s[i] = g[i];
    }
    __syncthreads();
#pragma unroll 8
    for (int d4 = 0; d4 < DC / 4; ++d4) {
      const float4 ev = *reinterpret_cast<const float4*>(&s_exp[lane][d4 * 4]);
#pragma unroll
      for (int t = 0; t < TW; ++t) {
        const float4 tv = *reinterpret_cast<const float4*>(&s_tok[wid * TW + t][d4 * 4]);
        acc[t][0] = fmaf(tv.x, ev.x, acc[t][0]);
        acc[t][1] = fmaf(tv.y, ev.y, acc[t][1]);
        acc[t][2] = fmaf(tv.z, ev.z, acc[t][2]);
        acc[t][3] = fmaf(tv.w, ev.w, acc[t][3]);
      }
    }
    __syncthreads();
  }

  s_sq[tr][tp] = sq;
  __syncthreads();
  if (tid < TB) {
    float ss = 0.f;
#pragma unroll
    for (int p = 0; p < 8; ++p) ss += s_sq[tid][p];
    s_tinv[tid] = 1.0f / (sqrtf(ss) + EPSV);
  }
  __syncthreads();

  // ---------- per-token selection (lane == expert, values one-per-lane) ----------
#pragma unroll 1
  for (int t = 0; t < TW; ++t) {
    const int trow = wid * TW + t;
    const float sim = (acc[t][0] + acc[t][1]) + (acc[t][2] + acc[t][3]);
    const float tinv = s_tinv[trow];

    // top-7 by sim, descending, ties -> lowest expert index (matches lax.top_k)
    float v = sim;
    int vi = lane;
    float cv[7];
    int ci[7];
#pragma unroll
    for (int r = 0; r < 7; ++r) {
      float rv = v;
      int ri = vi;
#pragma unroll
      for (int m = 32; m >= 1; m >>= 1) {
        float ov = __shfl_xor(rv, m);
        int oi = __shfl_xor(ri, m);
        if (ov > rv || (ov == rv && oi < ri)) { rv = ov; ri = oi; }
      }
      cv[r] = rv; ci[r] = ri;
      if (vi == ri) v = -INFINITY;  // mask winner in its owner lane
    }

    // reversed order l=0..6  <->  rank 6-l ; total = cos + 0.1*cache
    float tot[7];
    int gi[7];
#pragma unroll
    for (int l = 0; l < 7; ++l) {
      const int ce = ci[6 - l];
      const float ei = __shfl(einv, ce);
      const float bo = __shfl(bonus, ce);
      tot[l] = cv[6 - l] * tinv * ei + bo;
      gi[l] = ce;
    }

    // top-2 of tot, ties -> lowest l (stable like lax.top_k)
    float bv = tot[0]; int bl = 0; int bgi = gi[0];
#pragma unroll
    for (int l = 1; l < 7; ++l)
      if (tot[l] > bv) { bv = tot[l]; bl = l; bgi = gi[l]; }
    float sv = -INFINITY; int sgi = 0;
#pragma unroll
    for (int l = 0; l < 7; ++l) {
      if (l == bl) continue;
      if (tot[l] > sv) { sv = tot[l]; sgi = gi[l]; }
    }

    // reference emits [second-best, best]; weights = softmax([sv, bv])
    const float e1 = expf(sv - bv);
    const float z = 1.0f + e1;
    if (lane == 0) {
      const int token = bt + trow;
      out_idx[2 * token]     = (float)sgi;
      out_idx[2 * token + 1] = (float)bgi;
      out_w[2 * token]     = e1 / z;
      out_w[2 * token + 1] = 1.0f / z;
    }
  }
}

extern "C" void kernel_launch(void* const* d_in, const int* in_sizes, int n_in,
                              void* d_out, int out_size, void* d_ws, size_t ws_size,
                              hipStream_t stream) {
  const float* tok   = (const float*)d_in[0];
  const float* expw  = (const float*)d_in[1];
  const float* cache = (const float*)d_in[2];
  float* out = (float*)d_out;
  float* einv = (float*)d_ws;

  const int n_tok = in_sizes[0] / D;       // 32768
  const int n_out_idx = n_tok * 2;         // 65536

  expert_norm_kernel<<<E, 256, 0, stream>>>(expw, einv);
  gate_kernel<<<n_tok / TB, 256, 0, stream>>>(tok, expw, cache, einv,
                                              out, out + n_out_idx);
}